// Round 8
// baseline (879.153 us; speedup 1.0000x reference)
//
#include <hip/hip_runtime.h>
#include <hip/hip_bf16.h>

#define BB 32
#define CC 192
#define HH 64
#define WW 64
#define OO 192
#define EE 8
#define KTOT (CC*9)      // 1728
#define NSP (HH*WW)      // 4096
#define EWN (OO*CC*9)    // 331776 per expert

typedef __attribute__((ext_vector_type(8))) __bf16 bf16x8;
typedef __attribute__((ext_vector_type(4))) float f32x4;

// async global->LDS, 16B per lane (dest = wave-uniform base + lane*16)
__device__ __forceinline__ void gl_lds16(const void* g, void* l) {
    __builtin_amdgcn_global_load_lds(
        (const __attribute__((address_space(1))) unsigned int*)g,
        (__attribute__((address_space(3))) unsigned int*)l, 16, 0, 0);
}

// ---------------- kernel 1: fused transpose (NCHW f32 -> NHWC bf16) + global avg pool ----
__global__ __launch_bounds__(256) void transpose_pool_kernel(const float* __restrict__ x,
                                                             __bf16* __restrict__ xT,
                                                             float* __restrict__ pooled) {
    const int ct = blockIdx.x, h = blockIdx.y, b = blockIdx.z;
    const int c0 = ct * 64;
    __shared__ float T[64][65];
    const int t = threadIdx.x;
    const int cr = t >> 2, wq = t & 3;
    const float* xr = x + (((size_t)b * CC + c0 + cr) * HH + h) * WW;
    float ps = 0.f;
#pragma unroll
    for (int i = 0; i < 4; ++i) {
        float4 v = *(const float4*)(xr + (wq + i * 4) * 4);
        int wbase = (wq + i * 4) * 4;
        T[cr][wbase + 0] = v.x; T[cr][wbase + 1] = v.y;
        T[cr][wbase + 2] = v.z; T[cr][wbase + 3] = v.w;
        ps += v.x + v.y + v.z + v.w;
    }
    ps += __shfl_down(ps, 2);
    ps += __shfl_down(ps, 1);
    if (wq == 0) atomicAdd(pooled + b * CC + c0 + cr, ps);
    __syncthreads();
#pragma unroll
    for (int i = 0; i < 2; ++i) {
        int u = t + 256 * i;
        int w = u >> 3, ch = u & 7;
        bf16x8 o;
#pragma unroll
        for (int j = 0; j < 8; ++j) o[j] = (__bf16)T[ch * 8 + j][w];
        *(bf16x8*)(xT + (((size_t)b * HH + h) * WW + w) * CC + c0 + ch * 8) = o;
    }
}

// ---------------- kernel 2: mix expert weights -> bf16 (routing computed inline) ----
__global__ __launch_bounds__(256) void mix_kernel(const float* __restrict__ ew,
                                                  const float* __restrict__ pooled,
                                                  const float* __restrict__ rw,
                                                  const float* __restrict__ rb,
                                                  __bf16* __restrict__ wmT) {
    __shared__ float r[8 * EE];
    __shared__ float es[EE][KTOT];
    const int t = threadIdx.x;
    const int o = blockIdx.x;
    const int b0 = blockIdx.y * 8;
    const size_t base = (size_t)o * KTOT;
#pragma unroll
    for (int e = 0; e < EE; ++e)
        for (int s = t; s < KTOT; s += 256)
            es[e][s] = ew[(size_t)e * EWN + base + s];
    if (t < 64) {
        const int bl = t >> 3, e = t & 7;
        const float* pb = pooled + (b0 + bl) * CC;
        const float* we = rw + e * CC;
        float acc = 0.f;
        for (int c = 0; c < CC; ++c) acc += pb[c] * we[c];
        acc = acc * (1.0f / 4096.0f) + rb[e];
        r[bl * EE + e] = 1.0f / (1.0f + expf(-acc));
    }
    __syncthreads();
    for (int i = 0; i < 7; ++i) {
        int jl = t + 256 * i;
        if (jl >= KTOT) break;
        int c = jl % 192;
        int t9 = jl / 192;
        int s = c * 9 + t9;
        float w[EE];
#pragma unroll
        for (int e = 0; e < EE; ++e) w[e] = es[e][s];
#pragma unroll
        for (int bi = 0; bi < 8; ++bi) {
            float acc = 0.f;
#pragma unroll
            for (int e = 0; e < EE; ++e) acc += r[bi * EE + e] * w[e];
            wmT[(size_t)(b0 + bi) * EWN + base + jl] = (__bf16)acc;
        }
    }
}

// ---------------- kernel 3: NHWC implicit-GEMM conv, single-buffer / max-occupancy ----
// 192(o) x 128(n = 2 h-rows x 64 w), BK=64, 512 thr (8 waves 4Mx2N).
// Single 40 KiB LDS buffer -> 4 blocks/CU (160 KiB exactly) -> 32 waves/CU.
// Per step: {stage 5 gl_lds | vmcnt(0) | bar | ds_read + MFMA | bar}; TLP across
// the 4 independent blocks hides each block's drain.
#define A_ELEMS (192*64)
#define B_ELEMS (128*64)
#define BUFE (A_ELEMS + B_ELEMS)   // 20480 bf16 = 40960 B

__global__ __launch_bounds__(512, 8) void conv_kernel(const __bf16* __restrict__ xT,
                                                      const __bf16* __restrict__ wmT,
                                                      const __bf16* __restrict__ zp,
                                                      float* __restrict__ out) {
    extern __shared__ __bf16 smem[];   // BUFE = 40960 B

    // bijective XCD swizzle: 1024 blocks; each XCD gets 4 consecutive b x 32 h-pairs
    const int gid = blockIdx.x;              // 0..1023
    const int nid = (gid & 7) * 128 + (gid >> 3);
    const int b  = nid >> 5;                 // 0..31
    const int h0 = (nid & 31) * 2;           // 0,2,..,62

    const int t = threadIdx.x;
    const int lane = t & 63;
    const int wv = t >> 6;                   // 0..7
    const int wr = wv >> 1;                  // 0..3 (M quadrant: 48 rows)
    const int wc = wv & 1;                   // 0..1 (N half: one h-row)
    const int l15 = lane & 15, lch = lane >> 4;
    const int lrow = lane >> 3;              // 0..7
    const int offB = (((lane & 7) ^ lrow) << 4);   // pre-swizzled source byte offset

    const char* wmb = (const char*)(wmT + (size_t)b * (OO * KTOT));
    const char* xtb = (const char*)(xT + (size_t)b * (HH * WW * CC));
    const char* zpb = (const char*)zp;

    f32x4 acc[3][4];
#pragma unroll
    for (int mi = 0; mi < 3; ++mi)
#pragma unroll
        for (int ni = 0; ni < 4; ++ni) acc[mi][ni] = (f32x4){0.f, 0.f, 0.f, 0.f};

    for (int step = 0; step < 27; ++step) {
        // ---- stage A (3) + B (2) into the single buffer ----
        {
            const size_t kB = (size_t)step * 128;
#pragma unroll
            for (int i = 0; i < 3; ++i) {
                const int chunk = wv * 3 + i;
                const char* src = wmb + (size_t)(chunk * 8 + lrow) * (KTOT * 2) + kB + offB;
                gl_lds16(src, (void*)(smem + chunk * 512));
            }
            const int t9 = step / 3;
            const int cc = step - t9 * 3;
            const int kh = t9 / 3;
            const int kw = t9 - kh * 3;
            const int c0 = cc * 64;
#pragma unroll
            for (int i = 0; i < 2; ++i) {
                const int chunk = wv * 2 + i;
                const int n = chunk * 8 + lrow;          // 0..127
                const int hl = n >> 6;
                const int w = n & 63;
                const int hp = h0 + hl + kh - 1;
                const int wp = w + kw - 1;
                const bool ok = ((unsigned)hp < (unsigned)HH) && ((unsigned)wp < (unsigned)WW);
                const char* src = ok
                    ? xtb + ((size_t)(hp * WW + wp) * CC + c0) * 2 + offB
                    : zpb + offB;
                gl_lds16(src, (void*)(smem + A_ELEMS + chunk * 512));
            }
        }
        asm volatile("s_waitcnt vmcnt(0)" ::: "memory");
        __builtin_amdgcn_s_barrier();
        __builtin_amdgcn_sched_barrier(0);

        const __bf16* As = smem;
        const __bf16* Bs = smem + A_ELEMS;
#pragma unroll
        for (int kc = 0; kc < 2; ++kc) {
            bf16x8 a[3], bbf[4];
#pragma unroll
            for (int mi = 0; mi < 3; ++mi) {
                const int r = wr * 48 + mi * 16 + l15;
                const int col = (kc * 64 + lch * 16) ^ ((r & 7) << 4);
                a[mi] = *(const bf16x8*)((const char*)As + r * 128 + col);
            }
#pragma unroll
            for (int ni = 0; ni < 4; ++ni) {
                const int r = wc * 64 + ni * 16 + l15;
                const int col = (kc * 64 + lch * 16) ^ ((r & 7) << 4);
                bbf[ni] = *(const bf16x8*)((const char*)Bs + r * 128 + col);
            }
            __builtin_amdgcn_s_setprio(1);
#pragma unroll
            for (int mi = 0; mi < 3; ++mi)
#pragma unroll
                for (int ni = 0; ni < 4; ++ni)
                    acc[mi][ni] = __builtin_amdgcn_mfma_f32_16x16x32_bf16(
                        a[mi], bbf[ni], acc[mi][ni], 0, 0, 0);
            __builtin_amdgcn_s_setprio(0);
        }
        __builtin_amdgcn_s_barrier();
        __builtin_amdgcn_sched_barrier(0);
    }

    // epilogue: D layout col = lane&15, row = (lane>>4)*4 + j
    float* ob = out + (size_t)b * OO * NSP + (size_t)(h0 + wc) * WW;
#pragma unroll
    for (int mi = 0; mi < 3; ++mi)
#pragma unroll
        for (int ni = 0; ni < 4; ++ni)
#pragma unroll
            for (int j = 0; j < 4; ++j) {
                const int o = wr * 48 + mi * 16 + lch * 4 + j;
                const int w = ni * 16 + l15;
                ob[(size_t)o * NSP + w] = acc[mi][ni][j];
            }
}

extern "C" void kernel_launch(void* const* d_in, const int* in_sizes, int n_in,
                              void* d_out, int out_size, void* d_ws, size_t ws_size,
                              hipStream_t stream) {
    const float* x  = (const float*)d_in[0];
    const float* ew = (const float*)d_in[1];
    const float* rw = (const float*)d_in[2];
    const float* rb = (const float*)d_in[3];
    float* out = (float*)d_out;

    char* ws = (char*)d_ws;
    float*  pooled  = (float*)(ws + 0);                      // 24576 B
    __bf16* zp      = (__bf16*)(ws + 24576);                 // 1024 B
    __bf16* xT      = (__bf16*)(ws + 65536);                 // 50,331,648 B
    __bf16* wmT     = (__bf16*)(ws + 65536 + 50331648);      // 21,233,664 B

    // one memset covers pooled + zero page
    hipMemsetAsync(ws, 0, 25600, stream);

    hipFuncSetAttribute((const void*)conv_kernel,
                        hipFuncAttributeMaxDynamicSharedMemorySize, BUFE * 2);

    hipLaunchKernelGGL(transpose_pool_kernel, dim3(3, HH, BB), dim3(256), 0, stream,
                       x, xT, pooled);
    hipLaunchKernelGGL(mix_kernel, dim3(OO, 4), dim3(256), 0, stream,
                       ew, pooled, rw, rb, wmT);
    hipLaunchKernelGGL(conv_kernel, dim3(1024), dim3(512), BUFE * 2, stream,
                       xT, wmT, zp, out);
}

// Round 9
// 178.236 us; speedup vs baseline: 4.9325x; 4.9325x over previous
//
#include <hip/hip_runtime.h>
#include <hip/hip_bf16.h>

#define BB 32
#define CC 192
#define HH 64
#define WW 64
#define OO 192
#define EE 8
#define KTOT (CC*9)      // 1728
#define NSP (HH*WW)      // 4096
#define EWN (OO*CC*9)    // 331776 per expert

typedef __attribute__((ext_vector_type(8))) __bf16 bf16x8;
typedef __attribute__((ext_vector_type(4))) float f32x4;

// async global->LDS, 16B per lane (dest = wave-uniform base + lane*16)
__device__ __forceinline__ void gl_lds16(const void* g, void* l) {
    __builtin_amdgcn_global_load_lds(
        (const __attribute__((address_space(1))) unsigned int*)g,
        (__attribute__((address_space(3))) unsigned int*)l, 16, 0, 0);
}

// ---------------- kernel 1: fused transpose (NCHW f32 -> NHWC bf16) + global avg pool ----
__global__ __launch_bounds__(256) void transpose_pool_kernel(const float* __restrict__ x,
                                                             __bf16* __restrict__ xT,
                                                             float* __restrict__ pooled) {
    const int ct = blockIdx.x, h = blockIdx.y, b = blockIdx.z;
    const int c0 = ct * 64;
    __shared__ float T[64][65];
    const int t = threadIdx.x;
    const int cr = t >> 2, wq = t & 3;
    const float* xr = x + (((size_t)b * CC + c0 + cr) * HH + h) * WW;
    float ps = 0.f;
#pragma unroll
    for (int i = 0; i < 4; ++i) {
        float4 v = *(const float4*)(xr + (wq + i * 4) * 4);
        int wbase = (wq + i * 4) * 4;
        T[cr][wbase + 0] = v.x; T[cr][wbase + 1] = v.y;
        T[cr][wbase + 2] = v.z; T[cr][wbase + 3] = v.w;
        ps += v.x + v.y + v.z + v.w;
    }
    ps += __shfl_down(ps, 2);
    ps += __shfl_down(ps, 1);
    if (wq == 0) atomicAdd(pooled + b * CC + c0 + cr, ps);
    __syncthreads();
#pragma unroll
    for (int i = 0; i < 2; ++i) {
        int u = t + 256 * i;
        int w = u >> 3, ch = u & 7;
        bf16x8 o;
#pragma unroll
        for (int j = 0; j < 8; ++j) o[j] = (__bf16)T[ch * 8 + j][w];
        *(bf16x8*)(xT + (((size_t)b * HH + h) * WW + w) * CC + c0 + ch * 8) = o;
    }
}

// ---------------- kernel 2: mix expert weights -> bf16 (routing computed inline) ----
__global__ __launch_bounds__(256) void mix_kernel(const float* __restrict__ ew,
                                                  const float* __restrict__ pooled,
                                                  const float* __restrict__ rw,
                                                  const float* __restrict__ rb,
                                                  __bf16* __restrict__ wmT) {
    __shared__ float r[8 * EE];
    __shared__ float es[EE][KTOT];
    const int t = threadIdx.x;
    const int o = blockIdx.x;
    const int b0 = blockIdx.y * 8;
    const size_t base = (size_t)o * KTOT;
#pragma unroll
    for (int e = 0; e < EE; ++e)
        for (int s = t; s < KTOT; s += 256)
            es[e][s] = ew[(size_t)e * EWN + base + s];
    if (t < 64) {
        const int bl = t >> 3, e = t & 7;
        const float* pb = pooled + (b0 + bl) * CC;
        const float* we = rw + e * CC;
        float acc = 0.f;
        for (int c = 0; c < CC; ++c) acc += pb[c] * we[c];
        acc = acc * (1.0f / 4096.0f) + rb[e];
        r[bl * EE + e] = 1.0f / (1.0f + expf(-acc));
    }
    __syncthreads();
    for (int i = 0; i < 7; ++i) {
        int jl = t + 256 * i;
        if (jl >= KTOT) break;
        int c = jl % 192;
        int t9 = jl / 192;
        int s = c * 9 + t9;
        float w[EE];
#pragma unroll
        for (int e = 0; e < EE; ++e) w[e] = es[e][s];
#pragma unroll
        for (int bi = 0; bi < 8; ++bi) {
            float acc = 0.f;
#pragma unroll
            for (int e = 0; e < EE; ++e) acc += r[bi * EE + e] * w[e];
            wmT[(size_t)(b0 + bi) * EWN + base + jl] = (__bf16)acc;
        }
    }
}

// ---------------- kernel 3: NHWC implicit-GEMM conv ----------------
// Tile 192(o) x 128(n = 2 h-rows), BK=32, 256 thr (4 waves 2Mx2N, per-wave 96x64).
// LDS rows pack 2 logical rows (m, m+96) / (n, n+64) into 128B so the 8-slot XOR
// swizzle + 1KB gl_lds chunks still apply. dbuf 2x20KB -> 3 blocks/CU, 12 waves/CU.
#define A_ELEMS (96*64)    // 6144 elems = 12KB (96 rows x 128B)
#define B_ELEMS (64*64)    // 4096 elems =  8KB (64 rows x 128B)
#define BUFE (A_ELEMS + B_ELEMS)   // 10240 elems = 20480 B

__global__ __launch_bounds__(256, 3) void conv_kernel(const __bf16* __restrict__ xT,
                                                      const __bf16* __restrict__ wmT,
                                                      const __bf16* __restrict__ zp,
                                                      float* __restrict__ out) {
    extern __shared__ __bf16 smem[];   // 2 * BUFE = 40960 B

    // bijective XCD swizzle: 1024 blocks; each XCD gets 4 consecutive b x 32 h-pairs
    const int gid = blockIdx.x;              // 0..1023
    const int nid = (gid & 7) * 128 + (gid >> 3);
    const int b  = nid >> 5;                 // 0..31
    const int h0 = (nid & 31) * 2;           // 0,2,..,62

    const int t = threadIdx.x;
    const int lane = t & 63;
    const int wv = t >> 6;                   // 0..3
    const int wr = wv >> 1;                  // 0..1 (M half: 96 rows)
    const int wc = wv & 1;                   // 0..1 (N half: one h-row)
    const int l15 = lane & 15, lch = lane >> 4;
    const int lrow = lane >> 3;              // 0..7
    const int lphys = lane & 7;              // linear 16B slot this lane writes

    const char* wmb = (const char*)(wmT + (size_t)b * (OO * KTOT));
    const char* xtb = (const char*)(xT + (size_t)b * (HH * WW * CC));
    const char* zpb = (const char*)zp + lphys * 16;

    // ---- per-lane staging constants ----
    // A: 12 chunks, wave wv stages chunks wv*3..wv*3+2
    const char* asrc[3];
#pragma unroll
    for (int i = 0; i < 3; ++i) {
        const int row = wv * 24 + i * 8 + lrow;          // 0..95
        const int s = lphys ^ (row & 7);
        const int m = row + ((s >= 4) ? 96 : 0);
        asrc[i] = wmb + (size_t)m * (KTOT * 2) + (s & 3) * 16;
    }
    // B: 8 chunks, wave wv stages chunks wv*2..wv*2+1
    int brow_[2], bhl_[2], bks_[2];
#pragma unroll
    for (int i = 0; i < 2; ++i) {
        const int row = wv * 16 + i * 8 + lrow;          // 0..63  (= w)
        const int s = lphys ^ (row & 7);
        brow_[i] = row;
        bhl_[i] = (s >= 4) ? 1 : 0;
        bks_[i] = s & 3;
    }

    // ---- per-lane read constants (phys slot = (whalf*4+lch) ^ (row&7), row&7 = l15&7) ----
    const int aoff = l15 * 128 + (((wr << 2) + lch) ^ (l15 & 7)) * 16;
    const int boff = l15 * 128 + (((wc << 2) + lch) ^ (l15 & 7)) * 16;

    f32x4 acc[6][4];
#pragma unroll
    for (int mi = 0; mi < 6; ++mi)
#pragma unroll
        for (int ni = 0; ni < 4; ++ni) acc[mi][ni] = (f32x4){0.f, 0.f, 0.f, 0.f};

    auto STAGE = [&](int buf, int step) {
        const int tap = step / 6;            // 0..8
        const int cc = step - tap * 6;       // 0..5
        const int kh = tap / 3;
        const int kw = tap - kh * 3;
        __bf16* As = smem + buf * BUFE;
        __bf16* Bs = As + A_ELEMS;
#pragma unroll
        for (int i = 0; i < 3; ++i)
            gl_lds16(asrc[i] + step * 64, (void*)(As + (wv * 3 + i) * 512));
#pragma unroll
        for (int i = 0; i < 2; ++i) {
            const int hp = h0 + bhl_[i] + kh - 1;
            const int wp = brow_[i] + kw - 1;
            const bool ok = ((unsigned)hp < (unsigned)HH) && ((unsigned)wp < (unsigned)WW);
            const char* src = ok
                ? xtb + ((size_t)(hp * WW + wp) * CC + cc * 32 + bks_[i] * 8) * 2
                : zpb;
            gl_lds16(src, (void*)(Bs + (wv * 2 + i) * 512));
        }
    };

    STAGE(0, 0);                                          // 5 outstanding
    for (int step = 0; step < 54; ++step) {
        const int cur = step & 1;
        if (step < 53) {
            STAGE(cur ^ 1, step + 1);                     // -> 10 outstanding
            asm volatile("s_waitcnt vmcnt(5)" ::: "memory");  // cur's 5 landed
        } else {
            asm volatile("s_waitcnt vmcnt(0)" ::: "memory");
        }
        __builtin_amdgcn_s_barrier();
        __builtin_amdgcn_sched_barrier(0);

        const char* As = (const char*)(smem + cur * BUFE);
        const char* Bs = As + A_ELEMS * 2;
        bf16x8 bbf[4];
#pragma unroll
        for (int ni = 0; ni < 4; ++ni)
            bbf[ni] = *(const bf16x8*)(Bs + ni * 2048 + boff);
        __builtin_amdgcn_s_setprio(1);
#pragma unroll
        for (int mi = 0; mi < 6; ++mi) {
            bf16x8 a = *(const bf16x8*)(As + mi * 2048 + aoff);
#pragma unroll
            for (int ni = 0; ni < 4; ++ni)
                acc[mi][ni] = __builtin_amdgcn_mfma_f32_16x16x32_bf16(
                    a, bbf[ni], acc[mi][ni], 0, 0, 0);
        }
        __builtin_amdgcn_s_setprio(0);
        __builtin_amdgcn_s_barrier();
        __builtin_amdgcn_sched_barrier(0);
    }

    // epilogue: D layout col = lane&15, row = (lane>>4)*4 + j
    float* ob = out + (size_t)b * OO * NSP + (size_t)(h0 + wc) * WW;
#pragma unroll
    for (int mi = 0; mi < 6; ++mi)
#pragma unroll
        for (int ni = 0; ni < 4; ++ni)
#pragma unroll
            for (int j = 0; j < 4; ++j) {
                const int o = wr * 96 + mi * 16 + lch * 4 + j;
                const int w = ni * 16 + l15;
                ob[(size_t)o * NSP + w] = acc[mi][ni][j];
            }
}

extern "C" void kernel_launch(void* const* d_in, const int* in_sizes, int n_in,
                              void* d_out, int out_size, void* d_ws, size_t ws_size,
                              hipStream_t stream) {
    const float* x  = (const float*)d_in[0];
    const float* ew = (const float*)d_in[1];
    const float* rw = (const float*)d_in[2];
    const float* rb = (const float*)d_in[3];
    float* out = (float*)d_out;

    char* ws = (char*)d_ws;
    float*  pooled  = (float*)(ws + 0);                      // 24576 B
    __bf16* zp      = (__bf16*)(ws + 24576);                 // 1024 B
    __bf16* xT      = (__bf16*)(ws + 65536);                 // 50,331,648 B
    __bf16* wmT     = (__bf16*)(ws + 65536 + 50331648);      // 21,233,664 B

    // one memset covers pooled + zero page
    hipMemsetAsync(ws, 0, 25600, stream);

    hipFuncSetAttribute((const void*)conv_kernel,
                        hipFuncAttributeMaxDynamicSharedMemorySize, 2 * BUFE * 2);

    hipLaunchKernelGGL(transpose_pool_kernel, dim3(3, HH, BB), dim3(256), 0, stream,
                       x, xT, pooled);
    hipLaunchKernelGGL(mix_kernel, dim3(OO, 4), dim3(256), 0, stream,
                       ew, pooled, rw, rb, wmT);
    hipLaunchKernelGGL(conv_kernel, dim3(1024), dim3(256), 2 * BUFE * 2, stream,
                       xT, wmT, zp, out);
}

// Round 10
// 150.039 us; speedup vs baseline: 5.8595x; 1.1879x over previous
//
#include <hip/hip_runtime.h>
#include <hip/hip_bf16.h>

#define BB 32
#define CC 192
#define HH 64
#define WW 64
#define OO 192
#define EE 8
#define KTOT (CC*9)      // 1728
#define NSP (HH*WW)      // 4096
#define EWN (OO*CC*9)    // 331776 per expert

typedef __attribute__((ext_vector_type(8))) __bf16 bf16x8;
typedef __attribute__((ext_vector_type(4))) float f32x4;

// async global->LDS, 16B per lane (dest = wave-uniform base + lane*16)
__device__ __forceinline__ void gl_lds16(const void* g, void* l) {
    __builtin_amdgcn_global_load_lds(
        (const __attribute__((address_space(1))) unsigned int*)g,
        (__attribute__((address_space(3))) unsigned int*)l, 16, 0, 0);
}

// ---------------- kernel 1: fused transpose (NCHW f32 -> NHWC bf16) + global avg pool ----
// block = (h, b): full 192c x 64w slice. Reads 256B-coalesced rows, LDS transpose,
// coalesced bf16x8 NHWC writes, pool reduction from LDS (2 lanes/bank = free).
__global__ __launch_bounds__(256) void transpose_pool_kernel(const float* __restrict__ x,
                                                             __bf16* __restrict__ xT,
                                                             float* __restrict__ pooled) {
    const int h = blockIdx.x, b = blockIdx.y;
    __shared__ float T[CC][65];   // 49920 B
    const int t = threadIdx.x;
    const float* xb = x + (size_t)b * CC * NSP + h * WW;
#pragma unroll
    for (int i = 0; i < 12; ++i) {
        const int g = i * 256 + t;          // 0..3071
        const int c = g >> 4;
        const int w4 = (g & 15) * 4;
        float4 v = *(const float4*)(xb + (size_t)c * NSP + w4);
        T[c][w4 + 0] = v.x; T[c][w4 + 1] = v.y;
        T[c][w4 + 2] = v.z; T[c][w4 + 3] = v.w;
    }
    __syncthreads();
    if (t < CC) {
        float s = 0.f;
#pragma unroll 8
        for (int w = 0; w < WW; ++w) s += T[t][w];
        atomicAdd(pooled + b * CC + t, s);
    }
    // outputs: 1536 bf16x8 chunks; consecutive lanes -> consecutive c-groups (coalesced)
#pragma unroll
    for (int i = 0; i < 6; ++i) {
        const int ch = i * 256 + t;         // 0..1535
        const int w = ch / 24;
        const int cg = ch - w * 24;
        bf16x8 o;
#pragma unroll
        for (int j = 0; j < 8; ++j) o[j] = (__bf16)T[cg * 8 + j][w];
        *(bf16x8*)(xT + (((size_t)b * HH + h) * WW + w) * CC + cg * 8) = o;
    }
}

// ---------------- kernel 2: mix expert weights -> bf16 (no LDS stage; L2-hot ew reads) ----
// dest: wmT[b][o][(kh*3+kw)*192 + c]; src i = (o*192+c)*9 + (kh*3+kw)
// grid (192 o, 8 b-groups of 4). Routing recomputed wave-parallel per block (cheap).
__global__ __launch_bounds__(256) void mix_kernel(const float* __restrict__ ew,
                                                  const float* __restrict__ pooled,
                                                  const float* __restrict__ rw,
                                                  const float* __restrict__ rb,
                                                  __bf16* __restrict__ wmT) {
    __shared__ float r[4 * EE];
    const int t = threadIdx.x;
    const int o = blockIdx.x;
    const int b0 = blockIdx.y * 4;
    // routing for 4 batches x 8 experts: 32 pairs x 8 threads each
    if (t < 256) {
        const int p = t >> 3, q = t & 7;        // p<32 pair, q sub-worker
        if (p < 32) {
            const int bl = p >> 3, e = p & 7;
            const float* pb = pooled + (b0 + bl) * CC + q * 24;
            const float* we = rw + e * CC + q * 24;
            float s = 0.f;
#pragma unroll
            for (int c = 0; c < 24; ++c) s += pb[c] * we[c];
            s += __shfl_xor(s, 4);
            s += __shfl_xor(s, 2);
            s += __shfl_xor(s, 1);
            if (q == 0) {
                s = s * (1.0f / 4096.0f) + rb[e];
                r[bl * EE + e] = 1.0f / (1.0f + expf(-s));
            }
        }
    }
    __syncthreads();
    const size_t base = (size_t)o * KTOT;
    for (int i = 0; i < 7; ++i) {
        const int jl = t + 256 * i;
        if (jl >= KTOT) break;
        const int c = jl % 192;
        const int t9 = jl / 192;
        const int s = c * 9 + t9;
        float w8[EE];
#pragma unroll
        for (int e = 0; e < EE; ++e) w8[e] = ew[(size_t)e * EWN + base + s];
#pragma unroll
        for (int bi = 0; bi < 4; ++bi) {
            float acc = 0.f;
#pragma unroll
            for (int e = 0; e < EE; ++e) acc += r[bi * EE + e] * w8[e];
            wmT[(size_t)(b0 + bi) * EWN + base + jl] = (__bf16)acc;
        }
    }
}

// ---------------- kernel 3: NHWC implicit-GEMM conv (proven R3 structure) ----------------
// 192(o) x 128(n = 2 h-rows x 64 w), BK=64, 512 thr (8 waves 4Mx2N).
// dbuf 2x40KB -> 2 blocks/CU; depth-1 prefetch, counted vmcnt(5).
#define A_ELEMS (192*64)
#define B_ELEMS (128*64)
#define BUFE (A_ELEMS + B_ELEMS)   // 20480 bf16 = 40960 B

__global__ __launch_bounds__(512) void conv_kernel(const __bf16* __restrict__ xT,
                                                   const __bf16* __restrict__ wmT,
                                                   const __bf16* __restrict__ zp,
                                                   float* __restrict__ out) {
    extern __shared__ __bf16 smem[];   // 2 * BUFE = 81920 B

    // bijective XCD swizzle: 1024 blocks; each XCD gets 4 consecutive b x 32 h-pairs
    const int gid = blockIdx.x;              // 0..1023
    const int nid = (gid & 7) * 128 + (gid >> 3);
    const int b  = nid >> 5;                 // 0..31
    const int h0 = (nid & 31) * 2;           // 0,2,..,62

    const int t = threadIdx.x;
    const int lane = t & 63;
    const int wv = t >> 6;                   // 0..7
    const int wr = wv >> 1;                  // 0..3 (M quadrant: 48 rows)
    const int wc = wv & 1;                   // 0..1 (N half: one h-row)
    const int l15 = lane & 15, lch = lane >> 4;
    const int lrow = lane >> 3;              // 0..7
    const int offB = (((lane & 7) ^ lrow) << 4);   // pre-swizzled source byte offset

    const char* wmb = (const char*)(wmT + (size_t)b * (OO * KTOT));
    const char* xtb = (const char*)(xT + (size_t)b * (HH * WW * CC));
    const char* zpb = (const char*)zp;

    f32x4 acc[3][4];
#pragma unroll
    for (int mi = 0; mi < 3; ++mi)
#pragma unroll
        for (int ni = 0; ni < 4; ++ni) acc[mi][ni] = (f32x4){0.f, 0.f, 0.f, 0.f};

    auto STAGE = [&](int buf, int step) {
        const int t9 = step / 3;
        const int cc = step - t9 * 3;
        const int kh = t9 / 3;
        const int kw = t9 - kh * 3;
        const int c0 = cc * 64;
        __bf16* As = smem + buf * BUFE;
        __bf16* Bs = As + A_ELEMS;
        const size_t kB = (size_t)step * 128;
        // A: 24 chunks of 8 rows x 128B; this wave: 3
#pragma unroll
        for (int i = 0; i < 3; ++i) {
            const int chunk = wv * 3 + i;
            const char* src = wmb + (size_t)(chunk * 8 + lrow) * (KTOT * 2) + kB + offB;
            gl_lds16(src, (void*)(As + chunk * 512));
        }
        // B: 16 chunks of 8 rows x 128B; this wave: 2
#pragma unroll
        for (int i = 0; i < 2; ++i) {
            const int chunk = wv * 2 + i;
            const int n = chunk * 8 + lrow;          // 0..127
            const int hl = n >> 6;
            const int w = n & 63;
            const int hp = h0 + hl + kh - 1;
            const int wp = w + kw - 1;
            const bool ok = ((unsigned)hp < (unsigned)HH) && ((unsigned)wp < (unsigned)WW);
            const char* src = ok
                ? xtb + ((size_t)(hp * WW + wp) * CC + c0) * 2 + offB
                : zpb + offB;
            gl_lds16(src, (void*)(Bs + chunk * 512));
        }
    };

    STAGE(0, 0);                                          // 5 outstanding / wave
    for (int step = 0; step < 27; ++step) {
        const int cur = step & 1;
        if (step + 1 < 27) {
            STAGE(cur ^ 1, step + 1);                     // -> 10 outstanding
            asm volatile("s_waitcnt vmcnt(5)" ::: "memory");  // cur's 5 landed
        } else {
            asm volatile("s_waitcnt vmcnt(0)" ::: "memory");
        }
        __builtin_amdgcn_s_barrier();
        __builtin_amdgcn_sched_barrier(0);

        const __bf16* As = smem + cur * BUFE;
        const __bf16* Bs = As + A_ELEMS;
#pragma unroll
        for (int kc = 0; kc < 2; ++kc) {
            bf16x8 a[3], bbf[4];
#pragma unroll
            for (int mi = 0; mi < 3; ++mi) {
                const int r = wr * 48 + mi * 16 + l15;
                const int col = (kc * 64 + lch * 16) ^ ((r & 7) << 4);
                a[mi] = *(const bf16x8*)((const char*)As + r * 128 + col);
            }
#pragma unroll
            for (int ni = 0; ni < 4; ++ni) {
                const int r = wc * 64 + ni * 16 + l15;
                const int col = (kc * 64 + lch * 16) ^ ((r & 7) << 4);
                bbf[ni] = *(const bf16x8*)((const char*)Bs + r * 128 + col);
            }
            __builtin_amdgcn_s_setprio(1);
#pragma unroll
            for (int mi = 0; mi < 3; ++mi)
#pragma unroll
                for (int ni = 0; ni < 4; ++ni)
                    acc[mi][ni] = __builtin_amdgcn_mfma_f32_16x16x32_bf16(
                        a[mi], bbf[ni], acc[mi][ni], 0, 0, 0);
            __builtin_amdgcn_s_setprio(0);
        }
        __builtin_amdgcn_s_barrier();
        __builtin_amdgcn_sched_barrier(0);
    }

    // epilogue: D layout col = lane&15, row = (lane>>4)*4 + j
    float* ob = out + (size_t)b * OO * NSP + (size_t)(h0 + wc) * WW;
#pragma unroll
    for (int mi = 0; mi < 3; ++mi)
#pragma unroll
        for (int ni = 0; ni < 4; ++ni)
#pragma unroll
            for (int j = 0; j < 4; ++j) {
                const int o = wr * 48 + mi * 16 + lch * 4 + j;
                const int w = ni * 16 + l15;
                ob[(size_t)o * NSP + w] = acc[mi][ni][j];
            }
}

extern "C" void kernel_launch(void* const* d_in, const int* in_sizes, int n_in,
                              void* d_out, int out_size, void* d_ws, size_t ws_size,
                              hipStream_t stream) {
    const float* x  = (const float*)d_in[0];
    const float* ew = (const float*)d_in[1];
    const float* rw = (const float*)d_in[2];
    const float* rb = (const float*)d_in[3];
    float* out = (float*)d_out;

    char* ws = (char*)d_ws;
    float*  pooled  = (float*)(ws + 0);                      // 24576 B
    __bf16* zp      = (__bf16*)(ws + 24576);                 // 1024 B
    __bf16* xT      = (__bf16*)(ws + 65536);                 // 50,331,648 B
    __bf16* wmT     = (__bf16*)(ws + 65536 + 50331648);      // 21,233,664 B

    // one memset covers pooled + zero page
    hipMemsetAsync(ws, 0, 25600, stream);

    hipFuncSetAttribute((const void*)conv_kernel,
                        hipFuncAttributeMaxDynamicSharedMemorySize, 2 * BUFE * 2);

    hipLaunchKernelGGL(transpose_pool_kernel, dim3(HH, BB), dim3(256), 0, stream,
                       x, xT, pooled);
    hipLaunchKernelGGL(mix_kernel, dim3(OO, 8), dim3(256), 0, stream,
                       ew, pooled, rw, rb, wmT);
    hipLaunchKernelGGL(conv_kernel, dim3(1024), dim3(512), 2 * BUFE * 2, stream,
                       xT, wmT, zp, out);
}

// Round 11
// 138.551 us; speedup vs baseline: 6.3453x; 1.0829x over previous
//
#include <hip/hip_runtime.h>
#include <hip/hip_bf16.h>

#define BB 32
#define CC 192
#define HH 64
#define WW 64
#define OO 192
#define EE 8
#define KTOT (CC*9)      // 1728
#define NSP (HH*WW)      // 4096
#define EWN (OO*CC*9)    // 331776 per expert

typedef __attribute__((ext_vector_type(8))) __bf16 bf16x8;
typedef __attribute__((ext_vector_type(4))) float f32x4;

// async global->LDS, 16B per lane (dest = wave-uniform base + lane*16)
__device__ __forceinline__ void gl_lds16(const void* g, void* l) {
    __builtin_amdgcn_global_load_lds(
        (const __attribute__((address_space(1))) unsigned int*)g,
        (__attribute__((address_space(3))) unsigned int*)l, 16, 0, 0);
}

// ---------------- kernel 1: fused transpose (NCHW f32 -> NHWC bf16) + global avg pool ----
__global__ __launch_bounds__(256) void transpose_pool_kernel(const float* __restrict__ x,
                                                             __bf16* __restrict__ xT,
                                                             float* __restrict__ pooled) {
    const int h = blockIdx.x, b = blockIdx.y;
    __shared__ float T[CC][65];   // 49920 B
    const int t = threadIdx.x;
    const float* xb = x + (size_t)b * CC * NSP + h * WW;
#pragma unroll
    for (int i = 0; i < 12; ++i) {
        const int g = i * 256 + t;          // 0..3071
        const int c = g >> 4;
        const int w4 = (g & 15) * 4;
        float4 v = *(const float4*)(xb + (size_t)c * NSP + w4);
        T[c][w4 + 0] = v.x; T[c][w4 + 1] = v.y;
        T[c][w4 + 2] = v.z; T[c][w4 + 3] = v.w;
    }
    __syncthreads();
    if (t < CC) {
        float s = 0.f;
#pragma unroll 8
        for (int w = 0; w < WW; ++w) s += T[t][w];
        atomicAdd(pooled + b * CC + t, s);
    }
#pragma unroll
    for (int i = 0; i < 6; ++i) {
        const int ch = i * 256 + t;         // 0..1535
        const int w = ch / 24;
        const int cg = ch - w * 24;
        bf16x8 o;
#pragma unroll
        for (int j = 0; j < 8; ++j) o[j] = (__bf16)T[cg * 8 + j][w];
        *(bf16x8*)(xT + (((size_t)b * HH + h) * WW + w) * CC + cg * 8) = o;
    }
}

// ---------------- kernel 2: mix expert weights -> bf16 (LDS-staged, coalesced reads) ----
// dest: wmT[b][o][(kh*3+kw)*192 + c]; src i = (o*192+c)*9 + (kh*3+kw)
// grid (192 o, 8 b-groups of 4). ew window staged via float4 (coalesced);
// compute reads es at word-stride 9 -> gcd(9,32)=1 -> conflict-free.
__global__ __launch_bounds__(256) void mix_kernel(const float* __restrict__ ew,
                                                  const float* __restrict__ pooled,
                                                  const float* __restrict__ rw,
                                                  const float* __restrict__ rb,
                                                  __bf16* __restrict__ wmT) {
    __shared__ float r[4 * EE];
    __shared__ float es[EE * KTOT];   // 55296 B
    const int t = threadIdx.x;
    const int o = blockIdx.x;
    const int b0 = blockIdx.y * 4;
    const size_t base = (size_t)o * KTOT;
    // stage 8 expert windows, coalesced float4 (432 float4 per expert)
    for (int u = t; u < EE * (KTOT / 4); u += 256) {
        const int e = u / (KTOT / 4);
        const int s4 = u - e * (KTOT / 4);
        *(float4*)&es[e * KTOT + s4 * 4] =
            *(const float4*)(ew + (size_t)e * EWN + base + s4 * 4);
    }
    // routing for 4 batches x 8 experts: 32 pairs x 8 sub-workers
    {
        const int p = t >> 3, q = t & 7;
        if (p < 32) {
            const int bl = p >> 3, e = p & 7;
            const float* pb = pooled + (b0 + bl) * CC + q * 24;
            const float* we = rw + e * CC + q * 24;
            float s = 0.f;
#pragma unroll
            for (int c = 0; c < 24; ++c) s += pb[c] * we[c];
            s += __shfl_xor(s, 4);
            s += __shfl_xor(s, 2);
            s += __shfl_xor(s, 1);
            if (q == 0) {
                s = s * (1.0f / 4096.0f) + rb[e];
                r[bl * EE + e] = 1.0f / (1.0f + expf(-s));
            }
        }
    }
    __syncthreads();
    for (int i = 0; i < 7; ++i) {
        const int jl = t + 256 * i;
        if (jl >= KTOT) break;
        const int c = jl % 192;
        const int t9 = jl / 192;
        const int s = c * 9 + t9;
        float w8[EE];
#pragma unroll
        for (int e = 0; e < EE; ++e) w8[e] = es[e * KTOT + s];
#pragma unroll
        for (int bi = 0; bi < 4; ++bi) {
            float acc = 0.f;
#pragma unroll
            for (int e = 0; e < EE; ++e) acc += r[bi * EE + e] * w8[e];
            wmT[(size_t)(b0 + bi) * EWN + base + jl] = (__bf16)acc;
        }
    }
}

// ---------------- kernel 3: NHWC implicit-GEMM conv (proven R3 structure) ----------------
// 192(o) x 128(n = 2 h-rows x 64 w), BK=64, 512 thr (8 waves 4Mx2N).
// dbuf 2x40KB -> 2 blocks/CU; depth-1 prefetch, counted vmcnt(5).
#define A_ELEMS (192*64)
#define B_ELEMS (128*64)
#define BUFE (A_ELEMS + B_ELEMS)   // 20480 bf16 = 40960 B

__global__ __launch_bounds__(512) void conv_kernel(const __bf16* __restrict__ xT,
                                                   const __bf16* __restrict__ wmT,
                                                   const __bf16* __restrict__ zp,
                                                   float* __restrict__ out) {
    extern __shared__ __bf16 smem[];   // 2 * BUFE = 81920 B

    // bijective XCD swizzle: 1024 blocks; each XCD gets 4 consecutive b x 32 h-pairs
    const int gid = blockIdx.x;              // 0..1023
    const int nid = (gid & 7) * 128 + (gid >> 3);
    const int b  = nid >> 5;                 // 0..31
    const int h0 = (nid & 31) * 2;           // 0,2,..,62

    const int t = threadIdx.x;
    const int lane = t & 63;
    const int wv = t >> 6;                   // 0..7
    const int wr = wv >> 1;                  // 0..3 (M quadrant: 48 rows)
    const int wc = wv & 1;                   // 0..1 (N half: one h-row)
    const int l15 = lane & 15, lch = lane >> 4;
    const int lrow = lane >> 3;              // 0..7
    const int offB = (((lane & 7) ^ lrow) << 4);   // pre-swizzled source byte offset

    const char* wmb = (const char*)(wmT + (size_t)b * (OO * KTOT));
    const char* xtb = (const char*)(xT + (size_t)b * (HH * WW * CC));
    const char* zpb = (const char*)zp;

    f32x4 acc[3][4];
#pragma unroll
    for (int mi = 0; mi < 3; ++mi)
#pragma unroll
        for (int ni = 0; ni < 4; ++ni) acc[mi][ni] = (f32x4){0.f, 0.f, 0.f, 0.f};

    auto STAGE = [&](int buf, int step) {
        const int t9 = step / 3;
        const int cc = step - t9 * 3;
        const int kh = t9 / 3;
        const int kw = t9 - kh * 3;
        const int c0 = cc * 64;
        __bf16* As = smem + buf * BUFE;
        __bf16* Bs = As + A_ELEMS;
        const size_t kB = (size_t)step * 128;
#pragma unroll
        for (int i = 0; i < 3; ++i) {
            const int chunk = wv * 3 + i;
            const char* src = wmb + (size_t)(chunk * 8 + lrow) * (KTOT * 2) + kB + offB;
            gl_lds16(src, (void*)(As + chunk * 512));
        }
#pragma unroll
        for (int i = 0; i < 2; ++i) {
            const int chunk = wv * 2 + i;
            const int n = chunk * 8 + lrow;          // 0..127
            const int hl = n >> 6;
            const int w = n & 63;
            const int hp = h0 + hl + kh - 1;
            const int wp = w + kw - 1;
            const bool ok = ((unsigned)hp < (unsigned)HH) && ((unsigned)wp < (unsigned)WW);
            const char* src = ok
                ? xtb + ((size_t)(hp * WW + wp) * CC + c0) * 2 + offB
                : zpb + offB;
            gl_lds16(src, (void*)(Bs + chunk * 512));
        }
    };

    STAGE(0, 0);                                          // 5 outstanding / wave
    for (int step = 0; step < 27; ++step) {
        const int cur = step & 1;
        if (step + 1 < 27) {
            STAGE(cur ^ 1, step + 1);                     // -> 10 outstanding
            asm volatile("s_waitcnt vmcnt(5)" ::: "memory");  // cur's 5 landed
        } else {
            asm volatile("s_waitcnt vmcnt(0)" ::: "memory");
        }
        __builtin_amdgcn_s_barrier();
        __builtin_amdgcn_sched_barrier(0);

        const __bf16* As = smem + cur * BUFE;
        const __bf16* Bs = As + A_ELEMS;
#pragma unroll
        for (int kc = 0; kc < 2; ++kc) {
            bf16x8 a[3], bbf[4];
#pragma unroll
            for (int mi = 0; mi < 3; ++mi) {
                const int r = wr * 48 + mi * 16 + l15;
                const int col = (kc * 64 + lch * 16) ^ ((r & 7) << 4);
                a[mi] = *(const bf16x8*)((const char*)As + r * 128 + col);
            }
#pragma unroll
            for (int ni = 0; ni < 4; ++ni) {
                const int r = wc * 64 + ni * 16 + l15;
                const int col = (kc * 64 + lch * 16) ^ ((r & 7) << 4);
                bbf[ni] = *(const bf16x8*)((const char*)Bs + r * 128 + col);
            }
            __builtin_amdgcn_s_setprio(1);
#pragma unroll
            for (int mi = 0; mi < 3; ++mi)
#pragma unroll
                for (int ni = 0; ni < 4; ++ni)
                    acc[mi][ni] = __builtin_amdgcn_mfma_f32_16x16x32_bf16(
                        a[mi], bbf[ni], acc[mi][ni], 0, 0, 0);
            __builtin_amdgcn_s_setprio(0);
        }
        __builtin_amdgcn_s_barrier();
        __builtin_amdgcn_sched_barrier(0);
    }

    // epilogue: D layout col = lane&15, row = (lane>>4)*4 + j ; nontemporal stores
    float* ob = out + (size_t)b * OO * NSP + (size_t)(h0 + wc) * WW;
#pragma unroll
    for (int mi = 0; mi < 3; ++mi)
#pragma unroll
        for (int ni = 0; ni < 4; ++ni)
#pragma unroll
            for (int j = 0; j < 4; ++j) {
                const int o = wr * 48 + mi * 16 + lch * 4 + j;
                const int w = ni * 16 + l15;
                __builtin_nontemporal_store(acc[mi][ni][j], &ob[(size_t)o * NSP + w]);
            }
}

extern "C" void kernel_launch(void* const* d_in, const int* in_sizes, int n_in,
                              void* d_out, int out_size, void* d_ws, size_t ws_size,
                              hipStream_t stream) {
    const float* x  = (const float*)d_in[0];
    const float* ew = (const float*)d_in[1];
    const float* rw = (const float*)d_in[2];
    const float* rb = (const float*)d_in[3];
    float* out = (float*)d_out;

    char* ws = (char*)d_ws;
    float*  pooled  = (float*)(ws + 0);                      // 24576 B
    __bf16* zp      = (__bf16*)(ws + 24576);                 // 1024 B
    __bf16* xT      = (__bf16*)(ws + 65536);                 // 50,331,648 B
    __bf16* wmT     = (__bf16*)(ws + 65536 + 50331648);      // 21,233,664 B

    // one memset covers pooled + zero page
    hipMemsetAsync(ws, 0, 25600, stream);

    hipFuncSetAttribute((const void*)conv_kernel,
                        hipFuncAttributeMaxDynamicSharedMemorySize, 2 * BUFE * 2);

    hipLaunchKernelGGL(transpose_pool_kernel, dim3(HH, BB), dim3(256), 0, stream,
                       x, xT, pooled);
    hipLaunchKernelGGL(mix_kernel, dim3(OO, 8), dim3(256), 0, stream,
                       ew, pooled, rw, rb, wmT);
    hipLaunchKernelGGL(conv_kernel, dim3(1024), dim3(512), 2 * BUFE * 2, stream,
                       xT, wmT, zp, out);
}